// Round 13
// baseline (38.472 us; speedup 1.0000x reference)
//
#include <hip/hip_runtime.h>

#define NB1   123
#define NCSd  96
#define SW    538
#define TPB   256
#define BT    16
#define STPB  128

// ---------------- ws layout ----------------
// [0]  u32  count (# flagged elements)           (zeroed by k_norm block 0)
// [1]  f32  dW2 = max_j |W_j - 1|^2              (k_norm block 0)
// [2..18) f32 per-block partial max of ||K_j||^2 (k_norm block i -> slot 2+i)
// [18..18+B) u32 flagged element indices

// ---- R/dW partials: 16 blocks x 4 waves; wave handles rows wid and wid+64 ----
__global__ __launch_bounds__(256) void k_norm(const float* __restrict__ Kre,
                                              const float* __restrict__ Kim,
                                              const float* __restrict__ Lre,
                                              const float* __restrict__ Lim,
                                              float* __restrict__ ws) {
    __shared__ float part[4];
    const int tid = threadIdx.x;
    const int w = tid >> 6, l = tid & 63;
    const int wid = blockIdx.x * 4 + w;              // 0..63
    const int j1 = wid, j2 = wid + 64;
    const bool has2 = j2 < NB1;

    const float* kr1 = Kre + j1 * NB1; const float* ki1 = Kim + j1 * NB1;
    float a0 = kr1[l], b0 = ki1[l];
    float a1 = 0.f, b1 = 0.f;
    if (l < NB1 - 64) { a1 = kr1[l + 64]; b1 = ki1[l + 64]; }
    float c0 = 0.f, d0 = 0.f, c1 = 0.f, d1 = 0.f;
    if (has2) {
        const float* kr2 = Kre + j2 * NB1; const float* ki2 = Kim + j2 * NB1;
        c0 = kr2[l]; d0 = ki2[l];
        if (l < NB1 - 64) { c1 = kr2[l + 64]; d1 = ki2[l + 64]; }
    }
    float s1 = fmaf(a0, a0, b0 * b0) + fmaf(a1, a1, b1 * b1);
    float s2 = fmaf(c0, c0, d0 * d0) + fmaf(c1, c1, d1 * d1);
    #pragma unroll
    for (int off = 32; off; off >>= 1) {
        s1 += __shfl_xor(s1, off);
        s2 += __shfl_xor(s2, off);
    }
    float m2 = has2 ? fmaxf(s1, s2) : s1;
    if (l == 0) part[w] = m2;
    __syncthreads();
    if (tid == 0)
        ws[2 + blockIdx.x] = fmaxf(fmaxf(part[0], part[1]), fmaxf(part[2], part[3]));

    if (blockIdx.x == 0 && w == 0) {
        float dr = Lre[l] - 1.f, di = Lim[l];
        float d2 = fmaf(dr, dr, di * di);
        if (l + 64 < NB1) {
            float dr2 = Lre[l + 64] - 1.f, di2 = Lim[l + 64];
            d2 = fmaxf(d2, fmaf(dr2, dr2, di2 * di2));
        }
        #pragma unroll
        for (int off = 32; off; off >>= 1) d2 = fmaxf(d2, __shfl_xor(d2, off));
        if (l == 0) { ws[1] = d2; ((unsigned*)ws)[0] = 0u; }
    }
}

// ---- main: 2 elements per wave; 4 full-wave lds-DMA stages + reg tail;
//      direct action reads; in-wave closed-form certificate ----
__global__ __launch_bounds__(TPB) void k_fast(const float* __restrict__ action,
                                              const float* __restrict__ state,
                                              float* __restrict__ ws,
                                              float* __restrict__ out) {
    __shared__ __align__(16) float st[4][1088];      // 2 state rows per wave (1076 used)
    __shared__ float ev[4][256];                     // 2 bus histograms per wave

    const int tid = threadIdx.x;
    const int w = tid >> 6, l = tid & 63;
    const long g = (long)blockIdx.x * 4 + w;         // wave id = element pair

    const float4* G4 = (const float4*)(state + g * (2 * SW));    // 4304B: 16B aligned
    float4* st4 = (float4*)st[w];

    // ---- async global->LDS staging, width=16: dest = uniform base + lane*16 ----
#define GLDS(gofs, lofs)                                                     \
    __builtin_amdgcn_global_load_lds(                                        \
        (const __attribute__((address_space(1))) void*)(G4 + (gofs)),        \
        (__attribute__((address_space(3))) void*)(st4 + (lofs)), 16, 0, 0)
    GLDS(l, 0);
    GLDS(l + 64, 64);
    GLDS(l + 128, 128);
    GLDS(l + 192, 192);
#undef GLDS
    // tail 13 float4 via regs (no predicated lds-DMA)
    float4 v4 = make_float4(0.f, 0.f, 0.f, 0.f);
    const bool t4 = l < 269 - 256;
    if (t4) v4 = G4[l + 256];

    // certificate inputs (L2-hot, issue early)
    float r2p = (l < 16) ? ws[2 + l] : 0.f;
    float dw2 = ws[1];

    // zero ev while loads are in flight (LDS-only)
    ev[w][l] = 0.f; ev[w][l + 64] = 0.f;
    ev[w][l + 128] = 0.f; ev[w][l + 192] = 0.f;
    if (t4) st4[l + 256] = v4;

    // staged data is wave-private: vmcnt drain suffices (no barrier needed)
    asm volatile("s_waitcnt vmcnt(0)" ::: "memory");

    // ---- per-element phase: 32 lanes each ----
    const int e = l >> 5, li = l & 31;
    const long b = 2 * g + e;
    const float* srow = st[w] + e * SW;
    const float* actp = action + b * NCSd;           // coalesced per 32-lane group
    float* evp = ev[w] + e * 128;
    const float pr = srow[3];

    float cost = 0.f, usat = 0.f;
    #pragma unroll
    for (int s = 0; s < 3; ++s) {
        int i = li + 32 * s;
        float cap = srow[250 + 3 * i];               // stride-3: conflict-free
        float tl  = srow[251 + 3 * i];
        int   bus = (int)srow[252 + 3 * i];
        float a   = actp[i];
        float conn = cap > 0.f ? 1.f : 0.f;
        float mch = fminf(22.0f,  conn * (70.0f - cap) * 4.0f);   // /DT, DT=0.25
        float mds = fmaxf(-22.0f, conn * (15.0f - cap) * 4.0f);
        float p = fmaxf(fminf(22.17f * a, mch), mds);             // MAX_CS = -MIN_CS
        cost = fmaf(pr * p, 0.25f, cost);
        float nc = ceilf((cap + p * 0.25f) * 100.0f) * 0.01f;
        if (tl == 1.0f) { float d = nc - 70.0f; usat = fmaf(-10.0f * d, d, usat); }
        atomicAdd(&evp[bus], p);
    }

    // s2 = |1000*S|^2 = sum_k (ap+ev)^2 + rp^2  (DS in-order: atomics precede reads)
    float s2 = 0.f;
    #pragma unroll
    for (int s = 0; s < 4; ++s) {
        int k = li + 32 * s;
        if (k < NB1) {
            float apv = srow[4 + k] + evp[k];
            float rpv = srow[127 + k];
            s2 = fmaf(apv, apv, fmaf(rpv, rpv, s2));
        }
    }
    #pragma unroll
    for (int off = 16; off; off >>= 1) {
        s2   += __shfl_xor(s2, off);
        cost += __shfl_xor(cost, off);
        usat += __shfl_xor(usat, off);
    }

    // ---- certificate: closed-form threshold from slots (once per wave) ----
    #pragma unroll
    for (int off = 8; off; off >>= 1) r2p = fmaxf(r2p, __shfl_xor(r2p, off));
    float R  = sqrtf(__shfl(r2p, 0));
    float dW = sqrtf(dw2);
    // safe <=> x < t*(1-dW-t), t = 0.0495-dW  (exact inversion of dW + x/m(x) < 0.0495)
    float t = 0.0495f - dW;
    float q2max = -1.0f;
    if (t > 0.f && t < 1.0f - dW) {
        float xm = (t * (1.0f - dW - t) - 1e-7f) / 1.001f;   // undo fp-safety inflation
        if (xm > 0.f && R > 0.f) {
            float sm = xm / R * 1000.0f;                      // s-scale (S = s/1000)
            q2max = sm * sm;
        }
    }
    bool safe = s2 <= q2max;

    if (li == 0) out[b] = cost + usat;               // voltage term certified zero

    bool flagged = (li == 0) && !safe;
    unsigned long long mask = __ballot(flagged);
    if (mask) {
        int nf = __popcll(mask);
        int lead = __ffsll((long long)mask) - 1;
        unsigned base_ = 0;
        if (l == lead) base_ = atomicAdd((unsigned*)ws, (unsigned)nf);
        base_ = __shfl(base_, lead);
        if (flagged) {
            int rank = __popcll(mask & ((1ull << l) - 1ull));
            ((unsigned*)ws)[18 + base_ + rank] = (unsigned)b;
        }
    }
}

// ---- batched exact solve for flagged elements (expected: none) ----
__global__ __launch_bounds__(STPB) void k_solve(const float* __restrict__ action,
                                                const float* __restrict__ state,
                                                const float* __restrict__ Kre,
                                                const float* __restrict__ Kim,
                                                const float* __restrict__ Lre,
                                                const float* __restrict__ Lim,
                                                const float* __restrict__ ws,
                                                float* __restrict__ out) {
    __shared__ float ev[BT][STPB];
    __shared__ __align__(16) float2 cmat[STPB][BT + 2];
    __shared__ float vls[STPB][BT + 1];
    __shared__ float red[2];
    __shared__ unsigned idxs[BT];
    const unsigned count = ((const unsigned*)ws)[0];
    const int tid = threadIdx.x;
    const int j = tid;
    const bool jok = j < NB1;
    const float Wre = jok ? Lre[j] : 1.f;
    const float Wim = jok ? Lim[j] : 0.f;

    for (unsigned base = (unsigned)blockIdx.x * BT; base < count; base += (unsigned)gridDim.x * BT) {
        unsigned nv = count - base; if (nv > BT) nv = BT;
        if (tid < BT) {
            unsigned t = (unsigned)tid < nv ? (unsigned)tid : nv - 1;
            idxs[tid] = ((const unsigned*)ws)[18 + base + t];
        }
        for (int x = tid; x < BT * STPB; x += STPB) ((float*)ev)[x] = 0.f;
        __syncthreads();

        for (int task = tid; task < BT * NCSd; task += STPB) {
            int e = task / NCSd, i = task - e * NCSd;
            long b = (long)idxs[e];
            const float* srow = state + b * SW;
            float cap = srow[250 + 3 * i];
            int   bus = (int)srow[252 + 3 * i];
            float a   = action[b * NCSd + i];
            float conn = cap > 0.f ? 1.f : 0.f;
            float mch = fminf(22.0f,  conn * (70.0f - cap) * 4.0f);
            float mds = fmaxf(-22.0f, conn * (15.0f - cap) * 4.0f);
            float p = fmaxf(fminf(22.17f * a, mch), mds);
            atomicAdd(&ev[e][bus], p);
        }
        __syncthreads();

        float Sre[BT], Sim[BT], vr[BT], vi[BT];
        #pragma unroll
        for (int e = 0; e < BT; ++e) {
            long b = (long)idxs[e];
            float ap = jok ? state[b * SW + 4 + j]   : 0.f;
            float rp = jok ? state[b * SW + 127 + j] : 0.f;
            Sre[e] = (ap + ev[e][j]) * 0.001f;
            Sim[e] = rp * 0.001f;
            vr[e] = 1.f; vi[e] = 0.f;
        }
        for (int it = 0; it < 100; ++it) {
            #pragma unroll
            for (int e = 0; e < BT; ++e) {
                float d = vr[e] * vr[e] + vi[e] * vi[e];
                float inv = 1.0f / d;
                cmat[j][e] = make_float2((Sre[e] * vr[e] + Sim[e] * vi[e]) * inv,
                                         (Sre[e] * vi[e] - Sim[e] * vr[e]) * inv);
            }
            __syncthreads();
            float ar[BT], ai[BT];
            #pragma unroll
            for (int e = 0; e < BT; ++e) { ar[e] = Wre; ai[e] = Wim; }
            for (int k = 0; k < NB1; ++k) {
                float kr = jok ? Kre[j * NB1 + k] : 0.f;
                float ki = jok ? Kim[j * NB1 + k] : 0.f;
                const float4* crow = (const float4*)(&cmat[k][0]);
                #pragma unroll
                for (int eh = 0; eh < BT / 2; ++eh) {
                    float4 c2 = crow[eh];
                    ar[2*eh]   = fmaf(kr, c2.x, fmaf(-ki, c2.y, ar[2*eh]));
                    ai[2*eh]   = fmaf(kr, c2.y, fmaf( ki, c2.x, ai[2*eh]));
                    ar[2*eh+1] = fmaf(kr, c2.z, fmaf(-ki, c2.w, ar[2*eh+1]));
                    ai[2*eh+1] = fmaf(kr, c2.w, fmaf( ki, c2.z, ai[2*eh+1]));
                }
            }
            float md = 0.f;
            #pragma unroll
            for (int e = 0; e < BT; ++e) {
                float vmn = sqrtf(ar[e]*ar[e] + ai[e]*ai[e]);
                float vmo = sqrtf(vr[e]*vr[e] + vi[e]*vi[e]);
                md = fmaxf(md, fabsf(vmn - vmo));
                vr[e] = ar[e]; vi[e] = ai[e];
            }
            #pragma unroll
            for (int off = 32; off; off >>= 1) md = fmaxf(md, __shfl_xor(md, off));
            if ((tid & 63) == 0) red[tid >> 6] = md;
            __syncthreads();
            if (fmaxf(red[0], red[1]) < 1e-6f) break;
        }
        #pragma unroll
        for (int e = 0; e < BT; ++e) {
            float vm = sqrtf(vr[e]*vr[e] + vi[e]*vi[e]);
            vls[j][e] = jok ? fminf(0.f, 0.05f - fabsf(1.0f - vm)) : 0.f;
        }
        __syncthreads();
        if (tid < (int)nv) {
            float s = 0.f;
            for (int k = 0; k < NB1; ++k) s += vls[k][tid];
            long b = (long)idxs[tid];
            out[b] += 1000.0f * s;
        }
        __syncthreads();
    }
}

// ================= legacy full-solve path (used only if ws too small) =================
__global__ __launch_bounds__(STPB) void k_main(
    const float* __restrict__ action, const float* __restrict__ state,
    const float* __restrict__ Kre, const float* __restrict__ Kim,
    const float* __restrict__ Lre, const float* __restrict__ Lim,
    float* __restrict__ out)
{
    __shared__ float ev[BT][STPB];
    __shared__ float costs_s[BT];
    __shared__ float usat_s[BT];
    __shared__ __align__(16) float2 cmat[STPB][BT + 2];
    __shared__ float vls[STPB][BT + 1];
    __shared__ float red[2];
    const int tid = threadIdx.x;
    const int e0  = blockIdx.x * BT;
    for (int x = tid; x < BT * STPB; x += STPB) ((float*)ev)[x] = 0.f;
    if (tid < BT) { costs_s[tid] = 0.f; usat_s[tid] = 0.f; }
    __syncthreads();
    for (int task = tid; task < BT * NCSd; task += STPB) {
        int e = task / NCSd, i = task - e * NCSd;
        long b = (long)(e0 + e);
        const float* srow = state + b * SW;
        float cap = srow[250 + 3 * i], tleft = srow[251 + 3 * i];
        int bus = (int)srow[252 + 3 * i];
        float a = action[b * NCSd + i];
        float conn = cap > 0.f ? 1.f : 0.f;
        float mch = fminf(22.0f, conn * (70.0f - cap) * 4.0f);
        float mds = fmaxf(-22.0f, conn * (15.0f - cap) * 4.0f);
        float power = fmaxf(fminf(22.17f * a, mch), mds);
        atomicAdd(&costs_s[e], srow[3] * power * 0.25f);
        float nc = ceilf((cap + power * 0.25f) * 100.0f) * 0.01f;
        if (tleft == 1.0f) { float d = nc - 70.0f; atomicAdd(&usat_s[e], -10.0f * d * d); }
        atomicAdd(&ev[e][bus], power);
    }
    __syncthreads();
    const int j = tid;
    const bool jok = j < NB1;
    float Wre = jok ? Lre[j] : 1.0f, Wim = jok ? Lim[j] : 0.0f;
    float Sre[BT], Sim[BT], vr[BT], vi[BT];
    #pragma unroll
    for (int e = 0; e < BT; ++e) {
        long b = (long)(e0 + e);
        float ap = jok ? state[b * SW + 4 + j] : 0.f;
        float rp = jok ? state[b * SW + 127 + j] : 0.f;
        Sre[e] = (ap + ev[e][j]) * 0.001f; Sim[e] = rp * 0.001f;
        vr[e] = 1.f; vi[e] = 0.f;
    }
    for (int it = 0; it < 100; ++it) {
        #pragma unroll
        for (int e = 0; e < BT; ++e) {
            float d = vr[e]*vr[e] + vi[e]*vi[e];
            float inv = 1.0f / d;
            cmat[j][e] = make_float2((Sre[e]*vr[e] + Sim[e]*vi[e]) * inv,
                                     (Sre[e]*vi[e] - Sim[e]*vr[e]) * inv);
        }
        __syncthreads();
        float ar[BT], ai[BT];
        #pragma unroll
        for (int e = 0; e < BT; ++e) { ar[e] = Wre; ai[e] = Wim; }
        for (int k = 0; k < NB1; ++k) {
            float kr = jok ? Kre[j*NB1+k] : 0.f;
            float ki = jok ? Kim[j*NB1+k] : 0.f;
            const float4* crow = (const float4*)(&cmat[k][0]);
            #pragma unroll
            for (int eh = 0; eh < BT / 2; ++eh) {
                float4 c2 = crow[eh];
                ar[2*eh]   = fmaf(kr, c2.x, fmaf(-ki, c2.y, ar[2*eh]));
                ai[2*eh]   = fmaf(kr, c2.y, fmaf( ki, c2.x, ai[2*eh]));
                ar[2*eh+1] = fmaf(kr, c2.z, fmaf(-ki, c2.w, ar[2*eh+1]));
                ai[2*eh+1] = fmaf(kr, c2.w, fmaf( ki, c2.z, ai[2*eh+1]));
            }
        }
        float md = 0.f;
        #pragma unroll
        for (int e = 0; e < BT; ++e) {
            float vmn = sqrtf(ar[e]*ar[e] + ai[e]*ai[e]);
            float vmo = sqrtf(vr[e]*vr[e] + vi[e]*vi[e]);
            md = fmaxf(md, fabsf(vmn - vmo));
            vr[e] = ar[e]; vi[e] = ai[e];
        }
        #pragma unroll
        for (int off = 32; off > 0; off >>= 1) md = fmaxf(md, __shfl_xor(md, off));
        if ((tid & 63) == 0) red[tid >> 6] = md;
        __syncthreads();
        if (fmaxf(red[0], red[1]) < 1e-6f) break;
    }
    #pragma unroll
    for (int e = 0; e < BT; ++e) {
        float vm = sqrtf(vr[e]*vr[e] + vi[e]*vi[e]);
        vls[j][e] = jok ? fminf(0.f, 0.05f - fabsf(1.0f - vm)) : 0.f;
    }
    __syncthreads();
    if (tid < BT) {
        float s = 0.f;
        for (int k = 0; k < NB1; ++k) s += vls[k][tid];
        out[e0 + tid] = 1000.0f * s + costs_s[tid] + usat_s[tid];
    }
}

extern "C" void kernel_launch(void* const* d_in, const int* in_sizes, int n_in,
                              void* d_out, int out_size, void* d_ws, size_t ws_size,
                              hipStream_t stream) {
    const float* action = (const float*)d_in[0];
    const float* state  = (const float*)d_in[1];
    const float* Kre    = (const float*)d_in[2];
    const float* Kim    = (const float*)d_in[3];
    const float* Lre    = (const float*)d_in[4];
    const float* Lim    = (const float*)d_in[5];
    float* out = (float*)d_out;
    const int B = out_size;                        // 32768

    const size_t wsNeed = (size_t)(18 + B) * sizeof(unsigned);
    if (ws_size >= wsNeed) {
        float* ws = (float*)d_ws;
        hipLaunchKernelGGL(k_norm, dim3(16), dim3(256), 0, stream, Kre, Kim, Lre, Lim, ws);
        hipLaunchKernelGGL(k_fast, dim3(B / 8), dim3(TPB), 0, stream,
                           action, state, ws, out);
        hipLaunchKernelGGL(k_solve, dim3(16), dim3(STPB), 0, stream,
                           action, state, Kre, Kim, Lre, Lim, ws, out);
    } else {
        hipLaunchKernelGGL(k_main, dim3((B + BT - 1) / BT), dim3(STPB), 0, stream,
                           action, state, Kre, Kim, Lre, Lim, out);
    }
}

// Round 14
// 36.136 us; speedup vs baseline: 1.0647x; 1.0647x over previous
//
#include <hip/hip_runtime.h>

#define NB1   123
#define NCSd  96
#define SW    538
#define TPB   256
#define BT    16
#define STPB  128

// ---------------- ws layout ----------------
// [0]  f32  dW2 = max_j |W_j - 1|^2              (k_norm block 0)
// [1..17) f32 per-block partial max of ||K_j||^2 (k_norm block i -> slot 1+i)

// ---- R/dW partials: 16 blocks x 4 waves; wave handles rows wid and wid+64 ----
__global__ __launch_bounds__(256) void k_norm(const float* __restrict__ Kre,
                                              const float* __restrict__ Kim,
                                              const float* __restrict__ Lre,
                                              const float* __restrict__ Lim,
                                              float* __restrict__ ws) {
    __shared__ float part[4];
    const int tid = threadIdx.x;
    const int w = tid >> 6, l = tid & 63;
    const int wid = blockIdx.x * 4 + w;              // 0..63
    const int j1 = wid, j2 = wid + 64;
    const bool has2 = j2 < NB1;

    const float* kr1 = Kre + j1 * NB1; const float* ki1 = Kim + j1 * NB1;
    float a0 = kr1[l], b0 = ki1[l];
    float a1 = 0.f, b1 = 0.f;
    if (l < NB1 - 64) { a1 = kr1[l + 64]; b1 = ki1[l + 64]; }
    float c0 = 0.f, d0 = 0.f, c1 = 0.f, d1 = 0.f;
    if (has2) {
        const float* kr2 = Kre + j2 * NB1; const float* ki2 = Kim + j2 * NB1;
        c0 = kr2[l]; d0 = ki2[l];
        if (l < NB1 - 64) { c1 = kr2[l + 64]; d1 = ki2[l + 64]; }
    }
    float s1 = fmaf(a0, a0, b0 * b0) + fmaf(a1, a1, b1 * b1);
    float s2 = fmaf(c0, c0, d0 * d0) + fmaf(c1, c1, d1 * d1);
    #pragma unroll
    for (int off = 32; off; off >>= 1) {
        s1 += __shfl_xor(s1, off);
        s2 += __shfl_xor(s2, off);
    }
    float m2 = has2 ? fmaxf(s1, s2) : s1;
    if (l == 0) part[w] = m2;
    __syncthreads();
    if (tid == 0)
        ws[1 + blockIdx.x] = fmaxf(fmaxf(part[0], part[1]), fmaxf(part[2], part[3]));

    if (blockIdx.x == 0 && w == 0) {
        float dr = Lre[l] - 1.f, di = Lim[l];
        float d2 = fmaf(dr, dr, di * di);
        if (l + 64 < NB1) {
            float dr2 = Lre[l + 64] - 1.f, di2 = Lim[l + 64];
            d2 = fmaxf(d2, fmaf(dr2, dr2, di2 * di2));
        }
        #pragma unroll
        for (int off = 32; off; off >>= 1) d2 = fmaxf(d2, __shfl_xor(d2, off));
        if (l == 0) ws[0] = d2;
    }
}

// ---- main: 2 elements/wave, float4 staging, in-wave cert, inline wave-local
//      exact fallback (never taken); two-node graph, no flag list ----
__global__ __launch_bounds__(TPB, 7) void k_fast(const float* __restrict__ action,
                                                 const float* __restrict__ state,
                                                 const float* __restrict__ Kre,
                                                 const float* __restrict__ Kim,
                                                 const float* __restrict__ Lre,
                                                 const float* __restrict__ Lim,
                                                 const float* __restrict__ ws,
                                                 float* __restrict__ out) {
    __shared__ __align__(16) float st[4][1088];      // 2 state rows per wave (1076 used)
    __shared__ float ev[4][256];                     // 2 bus histograms per wave

    const int tid = threadIdx.x;
    const int w = tid >> 6, l = tid & 63;
    const long g = (long)blockIdx.x * 4 + w;         // wave id = element pair

    // ---- issue ALL global loads as dwordx4 before any use ----
    const float4* G4 = (const float4*)(state + g * (2 * SW));    // 4304B: 16B aligned
    float4 v0 = G4[l];
    float4 v1 = G4[l + 64];
    float4 v2 = G4[l + 128];
    float4 v3 = G4[l + 192];
    float4 v4 = make_float4(0.f, 0.f, 0.f, 0.f);
    const bool t4 = l < 269 - 256;                   // 13 tail lanes
    if (t4) v4 = G4[l + 256];

    // certificate inputs (L2-hot, issue early)
    float r2p = (l < 16) ? ws[1 + l] : 0.f;
    float dw2 = ws[0];

    // zero ev while loads are in flight (LDS-only)
    ev[w][l] = 0.f; ev[w][l + 64] = 0.f;
    ev[w][l + 128] = 0.f; ev[w][l + 192] = 0.f;

    // ---- LDS stores (hw waits vmcnt per dependence; DS pipe in-order per wave) ----
    float4* st4 = (float4*)st[w];
    st4[l] = v0; st4[l + 64] = v1; st4[l + 128] = v2; st4[l + 192] = v3;
    if (t4) st4[l + 256] = v4;

    // ---- per-element phase: 32 lanes each ----
    const int e = l >> 5, li = l & 31;
    const long b = 2 * g + e;
    const float* srow = st[w] + e * SW;
    const float* actp = action + b * NCSd;           // coalesced per 32-lane group
    float* evp = ev[w] + e * 128;
    const float pr = srow[3];

    float cost = 0.f, usat = 0.f;
    #pragma unroll
    for (int s = 0; s < 3; ++s) {
        int i = li + 32 * s;
        float cap = srow[250 + 3 * i];               // stride-3: conflict-free
        float tl  = srow[251 + 3 * i];
        int   bus = (int)srow[252 + 3 * i];
        float a   = actp[i];
        float conn = cap > 0.f ? 1.f : 0.f;
        float mch = fminf(22.0f,  conn * (70.0f - cap) * 4.0f);   // /DT, DT=0.25
        float mds = fmaxf(-22.0f, conn * (15.0f - cap) * 4.0f);
        float p = fmaxf(fminf(22.17f * a, mch), mds);             // MAX_CS = -MIN_CS
        cost = fmaf(pr * p, 0.25f, cost);
        float nc = ceilf((cap + p * 0.25f) * 100.0f) * 0.01f;
        if (tl == 1.0f) { float d = nc - 70.0f; usat = fmaf(-10.0f * d, d, usat); }
        atomicAdd(&evp[bus], p);
    }

    // s2 = |1000*S|^2 = sum_k (ap+ev)^2 + rp^2  (DS in-order: atomics precede reads)
    float s2 = 0.f;
    #pragma unroll
    for (int s = 0; s < 4; ++s) {
        int k = li + 32 * s;
        if (k < NB1) {
            float apv = srow[4 + k] + evp[k];
            float rpv = srow[127 + k];
            s2 = fmaf(apv, apv, fmaf(rpv, rpv, s2));
        }
    }
    #pragma unroll
    for (int off = 16; off; off >>= 1) {
        s2   += __shfl_xor(s2, off);
        cost += __shfl_xor(cost, off);
        usat += __shfl_xor(usat, off);
    }

    // ---- certificate: closed-form threshold from slots (once per wave) ----
    #pragma unroll
    for (int off = 8; off; off >>= 1) r2p = fmaxf(r2p, __shfl_xor(r2p, off));
    float R  = sqrtf(__shfl(r2p, 0));
    float dW = sqrtf(dw2);
    // safe <=> x < t*(1-dW-t), t = 0.0495-dW  (exact inversion of dW + x/m(x) < 0.0495)
    float t = 0.0495f - dW;
    float q2max = -1.0f;
    if (t > 0.f && t < 1.0f - dW) {
        float xm = (t * (1.0f - dW - t) - 1e-7f) / 1.001f;   // undo fp-safety inflation
        if (xm > 0.f && R > 0.f) {
            float sm = xm / R * 1000.0f;                      // s-scale (S = s/1000)
            q2max = sm * sm;
        }
    }
    bool safe = s2 <= q2max;

    // ---- inline exact fallback: wave-uniform branch, expected never taken ----
    float vs0 = 0.f, vs1 = 0.f;                      // voltage-loss sums per element
    unsigned long long bad = __ballot(!safe);        // bit0 = e0 verdict, bit32 = e1
    if (bad & 0x100000001ull) {
        const int j1 = l, j2 = 64 + l;
        const bool has2 = j2 < NB1;                  // l < 59
        float* cw = st[w];                           // reuse [0..255] as c scratch
        #pragma unroll 1
        for (int fe = 0; fe < 2; ++fe) {
            if (!((bad >> (fe * 32)) & 1ull)) continue;
            const float* frow = st[w] + fe * SW;
            float* fev = ev[w] + fe * 128;
            // extract S into regs BEFORE trashing st[w][0..255]
            float S1r = (frow[4 + j1] + fev[j1]) * 0.001f;
            float S1i = frow[127 + j1] * 0.001f;
            float S2r = has2 ? (frow[4 + j2] + fev[j2]) * 0.001f : 0.f;
            float S2i = has2 ? frow[127 + j2] * 0.001f : 0.f;
            float W1r = Lre[j1], W1i = Lim[j1];
            float W2r = has2 ? Lre[j2] : 1.f;
            float W2i = has2 ? Lim[j2] : 0.f;
            float v1r = 1.f, v1i = 0.f, v2r = 1.f, v2i = 0.f;
            for (int it = 0; it < 32; ++it) {        // fp32 fixpoint well before 32
                float d1 = v1r * v1r + v1i * v1i, i1 = 1.0f / d1;
                cw[j1]       = (S1r * v1r + S1i * v1i) * i1;
                cw[128 + j1] = (S1r * v1i - S1i * v1r) * i1;
                if (has2) {
                    float d2 = v2r * v2r + v2i * v2i, i2 = 1.0f / d2;
                    cw[j2]       = (S2r * v2r + S2i * v2i) * i2;
                    cw[128 + j2] = (S2r * v2i - S2i * v2r) * i2;
                }
                asm volatile("s_waitcnt lgkmcnt(0)" ::: "memory");
                float a1r = W1r, a1i = W1i, a2r = W2r, a2i = W2i;
                for (int k = 0; k < NB1; ++k) {
                    float cr = cw[k], ci = cw[128 + k];
                    float kr1 = Kre[j1 * NB1 + k], ki1 = Kim[j1 * NB1 + k];
                    a1r = fmaf(kr1, cr, fmaf(-ki1, ci, a1r));
                    a1i = fmaf(kr1, ci, fmaf( ki1, cr, a1i));
                    if (has2) {
                        float kr2 = Kre[j2 * NB1 + k], ki2 = Kim[j2 * NB1 + k];
                        a2r = fmaf(kr2, cr, fmaf(-ki2, ci, a2r));
                        a2i = fmaf(kr2, ci, fmaf( ki2, cr, a2i));
                    }
                }
                v1r = a1r; v1i = a1i; v2r = a2r; v2i = a2i;
                asm volatile("s_waitcnt lgkmcnt(0)" ::: "memory");
            }
            float vm1 = sqrtf(v1r * v1r + v1i * v1i);
            float vl = fminf(0.f, 0.05f - fabsf(1.0f - vm1));
            if (has2) {
                float vm2 = sqrtf(v2r * v2r + v2i * v2i);
                vl += fminf(0.f, 0.05f - fabsf(1.0f - vm2));
            }
            #pragma unroll
            for (int off = 32; off; off >>= 1) vl += __shfl_xor(vl, off);
            if (fe == 0) vs0 = vl; else vs1 = vl;
        }
    }

    if (li == 0) out[b] = cost + usat + 1000.0f * (e == 0 ? vs0 : vs1);
}

// ================= legacy full-solve path (used only if ws too small) =================
__global__ __launch_bounds__(STPB) void k_main(
    const float* __restrict__ action, const float* __restrict__ state,
    const float* __restrict__ Kre, const float* __restrict__ Kim,
    const float* __restrict__ Lre, const float* __restrict__ Lim,
    float* __restrict__ out)
{
    __shared__ float ev[BT][STPB];
    __shared__ float costs_s[BT];
    __shared__ float usat_s[BT];
    __shared__ __align__(16) float2 cmat[STPB][BT + 2];
    __shared__ float vls[STPB][BT + 1];
    __shared__ float red[2];
    const int tid = threadIdx.x;
    const int e0  = blockIdx.x * BT;
    for (int x = tid; x < BT * STPB; x += STPB) ((float*)ev)[x] = 0.f;
    if (tid < BT) { costs_s[tid] = 0.f; usat_s[tid] = 0.f; }
    __syncthreads();
    for (int task = tid; task < BT * NCSd; task += STPB) {
        int e = task / NCSd, i = task - e * NCSd;
        long b = (long)(e0 + e);
        const float* srow = state + b * SW;
        float cap = srow[250 + 3 * i], tleft = srow[251 + 3 * i];
        int bus = (int)srow[252 + 3 * i];
        float a = action[b * NCSd + i];
        float conn = cap > 0.f ? 1.f : 0.f;
        float mch = fminf(22.0f, conn * (70.0f - cap) * 4.0f);
        float mds = fmaxf(-22.0f, conn * (15.0f - cap) * 4.0f);
        float power = fmaxf(fminf(22.17f * a, mch), mds);
        atomicAdd(&costs_s[e], srow[3] * power * 0.25f);
        float nc = ceilf((cap + power * 0.25f) * 100.0f) * 0.01f;
        if (tleft == 1.0f) { float d = nc - 70.0f; atomicAdd(&usat_s[e], -10.0f * d * d); }
        atomicAdd(&ev[e][bus], power);
    }
    __syncthreads();
    const int j = tid;
    const bool jok = j < NB1;
    float Wre = jok ? Lre[j] : 1.0f, Wim = jok ? Lim[j] : 0.0f;
    float Sre[BT], Sim[BT], vr[BT], vi[BT];
    #pragma unroll
    for (int e = 0; e < BT; ++e) {
        long b = (long)(e0 + e);
        float ap = jok ? state[b * SW + 4 + j] : 0.f;
        float rp = jok ? state[b * SW + 127 + j] : 0.f;
        Sre[e] = (ap + ev[e][j]) * 0.001f; Sim[e] = rp * 0.001f;
        vr[e] = 1.f; vi[e] = 0.f;
    }
    for (int it = 0; it < 100; ++it) {
        #pragma unroll
        for (int e = 0; e < BT; ++e) {
            float d = vr[e]*vr[e] + vi[e]*vi[e];
            float inv = 1.0f / d;
            cmat[j][e] = make_float2((Sre[e]*vr[e] + Sim[e]*vi[e]) * inv,
                                     (Sre[e]*vi[e] - Sim[e]*vr[e]) * inv);
        }
        __syncthreads();
        float ar[BT], ai[BT];
        #pragma unroll
        for (int e = 0; e < BT; ++e) { ar[e] = Wre; ai[e] = Wim; }
        for (int k = 0; k < NB1; ++k) {
            float kr = jok ? Kre[j*NB1+k] : 0.f;
            float ki = jok ? Kim[j*NB1+k] : 0.f;
            const float4* crow = (const float4*)(&cmat[k][0]);
            #pragma unroll
            for (int eh = 0; eh < BT / 2; ++eh) {
                float4 c2 = crow[eh];
                ar[2*eh]   = fmaf(kr, c2.x, fmaf(-ki, c2.y, ar[2*eh]));
                ai[2*eh]   = fmaf(kr, c2.y, fmaf( ki, c2.x, ai[2*eh]));
                ar[2*eh+1] = fmaf(kr, c2.z, fmaf(-ki, c2.w, ar[2*eh+1]));
                ai[2*eh+1] = fmaf(kr, c2.w, fmaf( ki, c2.z, ai[2*eh+1]));
            }
        }
        float md = 0.f;
        #pragma unroll
        for (int e = 0; e < BT; ++e) {
            float vmn = sqrtf(ar[e]*ar[e] + ai[e]*ai[e]);
            float vmo = sqrtf(vr[e]*vr[e] + vi[e]*vi[e]);
            md = fmaxf(md, fabsf(vmn - vmo));
            vr[e] = ar[e]; vi[e] = ai[e];
        }
        #pragma unroll
        for (int off = 32; off > 0; off >>= 1) md = fmaxf(md, __shfl_xor(md, off));
        if ((tid & 63) == 0) red[tid >> 6] = md;
        __syncthreads();
        if (fmaxf(red[0], red[1]) < 1e-6f) break;
    }
    #pragma unroll
    for (int e = 0; e < BT; ++e) {
        float vm = sqrtf(vr[e]*vr[e] + vi[e]*vi[e]);
        vls[j][e] = jok ? fminf(0.f, 0.05f - fabsf(1.0f - vm)) : 0.f;
    }
    __syncthreads();
    if (tid < BT) {
        float s = 0.f;
        for (int k = 0; k < NB1; ++k) s += vls[k][tid];
        out[e0 + tid] = 1000.0f * s + costs_s[tid] + usat_s[tid];
    }
}

extern "C" void kernel_launch(void* const* d_in, const int* in_sizes, int n_in,
                              void* d_out, int out_size, void* d_ws, size_t ws_size,
                              hipStream_t stream) {
    const float* action = (const float*)d_in[0];
    const float* state  = (const float*)d_in[1];
    const float* Kre    = (const float*)d_in[2];
    const float* Kim    = (const float*)d_in[3];
    const float* Lre    = (const float*)d_in[4];
    const float* Lim    = (const float*)d_in[5];
    float* out = (float*)d_out;
    const int B = out_size;                        // 32768

    if (ws_size >= 17 * sizeof(float)) {
        float* ws = (float*)d_ws;
        hipLaunchKernelGGL(k_norm, dim3(16), dim3(256), 0, stream, Kre, Kim, Lre, Lim, ws);
        hipLaunchKernelGGL(k_fast, dim3(B / 8), dim3(TPB), 0, stream,
                           action, state, Kre, Kim, Lre, Lim, ws, out);
    } else {
        hipLaunchKernelGGL(k_main, dim3((B + BT - 1) / BT), dim3(STPB), 0, stream,
                           action, state, Kre, Kim, Lre, Lim, out);
    }
}